// Round 8
// baseline (233.343 us; speedup 1.0000x reference)
//
#include <hip/hip_runtime.h>
#include <float.h>

typedef __bf16 bf16x8 __attribute__((ext_vector_type(8)));
typedef __bf16 bf16x4 __attribute__((ext_vector_type(4)));
typedef float  f32x4  __attribute__((ext_vector_type(4)));

#define G      256
#define MT     64      // points per block-tile (2 point-groups x 32)
#define H1DIM  64
#define H2DIM  128
#define LAT    256
#define H1PAD  72      // 144 B rows: 16B-aligned
#define H2PAD  136     // 272 B rows: 16B-aligned

// DS-only barrier: LDS visibility needs lgkmcnt(0) only; skipping the vmcnt drain
// keeps the register point-prefetch in flight (measured neutral vs __syncthreads in
// r7, kept because it is never worse and the prefetch discipline is free).
__device__ __forceinline__ void barrier_lgkm() {
  asm volatile("s_waitcnt lgkmcnt(0)" ::: "memory");
  __builtin_amdgcn_s_barrier();
  asm volatile("" ::: "memory");
}

// order-preserving float->uint map: max on uints == max on floats
__device__ __forceinline__ unsigned mapf(float f) {
  unsigned u = __float_as_uint(f);
  return (u & 0x80000000u) ? ~u : (u | 0x80000000u);
}
__device__ __forceinline__ float unmapf(unsigned u) {
  return (u & 0x80000000u) ? __uint_as_float(u & 0x7fffffffu) : __uint_as_float(~u);
}

// flush the wave's 64 latent features (4 m-tiles): add bias, reduce over the 16
// point-lanes, atomicMax to pooled[s]. Vectors BY VALUE (no address-taken).
// A wave whose point-group has no points of segment s flushes -FLT_MAX+b3; the
// wave that owns the points flushes the real max, which wins the atomicMax.
__device__ __forceinline__ void flush4(f32x4 v0, f32x4 v1, f32x4 v2, f32x4 v3,
                                       int s, int fg, int q, int nn,
                                       const float* __restrict__ b3,
                                       unsigned* __restrict__ pooled) {
  f32x4 vv[4] = {v0, v1, v2, v3};
  #pragma unroll
  for (int mt = 0; mt < 4; ++mt)
    #pragma unroll
    for (int r = 0; r < 4; ++r) {
      int feat = fg * 64 + mt * 16 + q * 4 + r;
      float v = vv[mt][r] + b3[feat];
      v = fmaxf(v, __shfl_xor(v, 1));
      v = fmaxf(v, __shfl_xor(v, 2));
      v = fmaxf(v, __shfl_xor(v, 4));
      v = fmaxf(v, __shfl_xor(v, 8));
      if (nn == 0) atomicMax(&pooled[s * LAT + feat], mapf(v));
    }
}

// ---------------- fused centroid + MLP + segment max: 2D wave split ----------------
// r7 accounting: feature-only split (F=8) makes all 8 waves read IDENTICAL B-operand
// activation fragments -> 96 KB LDS reads per 32-pt tile (3.4 KB/pt), ~70% of the
// CU-shared LDS pipe -> wall invariant to occupancy/barriers (r1/r7 nulls).
// This kernel: 8 waves = 4 feature-groups (fg) x 2 point-groups (pg), 64-pt tiles.
// Each wave reads only its point-half's activations: 1.5 KB/pt reads (2.3x less),
// half the barriers per point. Weights stay in REGISTERS (r2-r6 lesson: weights-in-
// LDS puts ds_reads on the MFMA critical path). w3f = 64 VGPR is the price;
// __launch_bounds__(512,2) -> 1 block/CU, 8 waves.
// Wave w: fg = w>>1 owns feats L1 [fg*16,+16) L2 [fg*32,+32) L3 [fg*64,+64);
//         pg = w&1  owns points [pg*32,+32) of the tile (2 MFMA columns).
__global__ __launch_bounds__(512, 2) void mlp_kernel(
    const float* __restrict__ pc,
    const float* __restrict__ W1, const float* __restrict__ b1,
    const float* __restrict__ W2, const float* __restrict__ b2,
    const float* __restrict__ W3, const float* __restrict__ b3,
    const int* __restrict__ sid,
    unsigned* __restrict__ pooled,
    float* __restrict__ sums,
    int n, int tiles_per_block) {
  __shared__ __align__(16) __bf16 shF[MT][8];
  __shared__ __align__(16) __bf16 sh1[MT][H1PAD];
  __shared__ __align__(16) __bf16 sh2[MT][H2PAD];
  __shared__ int segt[MT];

  const int t    = threadIdx.x;
  const int w    = t >> 6;       // wave 0..7
  const int fg   = w >> 1;       // feature group 0..3
  const int pg   = w & 1;        // point group 0..1
  const int lane = t & 63;
  const int q    = lane >> 4;
  const int nn   = lane & 15;

  // ---- persistent weight fragments (A-operand: A[m=nn][k=q*8+j]) ----
  bf16x8 w1f;                    // 16 L1 feats, K=32 zero-padded (real K=4)
  #pragma unroll
  for (int j = 0; j < 8; ++j) {
    int k = q * 8 + j;
    w1f[j] = (k < 4) ? (__bf16)W1[k * H1DIM + fg * 16 + nn] : (__bf16)0.f;
  }
  float b1r[4];
  #pragma unroll
  for (int r = 0; r < 4; ++r) b1r[r] = b1[fg * 16 + q * 4 + r];

  bf16x8 w2f[2][2];              // [mt][ks]; 32 L2 feats
  float  b2r[2][4];
  #pragma unroll
  for (int mt = 0; mt < 2; ++mt) {
    int m = fg * 32 + mt * 16 + nn;
    #pragma unroll
    for (int ks = 0; ks < 2; ++ks)
      #pragma unroll
      for (int j = 0; j < 8; ++j)
        w2f[mt][ks][j] = (__bf16)W2[(ks * 32 + q * 8 + j) * H2DIM + m];
    #pragma unroll
    for (int r = 0; r < 4; ++r) b2r[mt][r] = b2[fg * 32 + mt * 16 + q * 4 + r];
  }

  bf16x8 w3f[4][4];              // [mt][ks]; 64 latent feats
  #pragma unroll
  for (int mt = 0; mt < 4; ++mt) {
    int m = fg * 64 + mt * 16 + nn;
    #pragma unroll
    for (int ks = 0; ks < 4; ++ks)
      #pragma unroll
      for (int j = 0; j < 8; ++j)
        w3f[mt][ks][j] = (__bf16)W3[(ks * 32 + q * 8 + j) * LAT + m];
  }

  const f32x4 zero4 = {0.f, 0.f, 0.f, 0.f};
  const bf16x8 zero8 = {};
  const f32x4 neginf4 = {-FLT_MAX, -FLT_MAX, -FLT_MAX, -FLT_MAX};

  f32x4 run[4];                  // running segment max (bias NOT included)
  #pragma unroll
  for (int mt = 0; mt < 4; ++mt) run[mt] = neginf4;

  // centroid state (wave 0, one point-stream per lane)
  float cx = 0.f, cy = 0.f, cz = 0.f, cc = 0.f;
  int   cseg = -1;

  const int tile0 = blockIdx.x * tiles_per_block;
  int first = tile0 * MT; if (first > n - 1) first = n - 1;
  int s_cur = sid[first];

  // ---- register prefetch of tile 0 (wave 0: 64 lanes, one point each) ----
  float pf1 = 0.f, pf2 = 0.f, pf3 = 0.f, pfx = 0.f;
  int   pfs = 0; bool pfv = false;
  if (w == 0) {
    int p = tile0 * MT + lane;
    pfv = p < n;
    int pcl = pfv ? p : (n - 1);
    const float* pp = pc + (size_t)pcl * 5;
    pf1 = pp[1]; pf2 = pp[2]; pf3 = pp[3]; pfx = pp[4];
    pfs = sid[pcl];
  }

  for (int ti = 0; ti < tiles_per_block; ++ti) {
    const int base = (tile0 + ti) * MT;
    if (base >= n) break;

    // ---- commit prefetched tile to LDS; centroid accumulation (wave 0) ----
    if (w == 0) {
      bf16x8 v = {};
      v[0] = (__bf16)pfx;   // x first (concat order!)
      v[1] = (__bf16)pf1;
      v[2] = (__bf16)pf2;
      v[3] = (__bf16)pf3;
      *reinterpret_cast<bf16x8*>(&shF[lane][0]) = v;
      segt[lane] = pfs;
      if (pfv) {
        if (pfs != cseg) {
          if (cc > 0.f) {
            atomicAdd(&sums[cseg * 4 + 0], cx);
            atomicAdd(&sums[cseg * 4 + 1], cy);
            atomicAdd(&sums[cseg * 4 + 2], cz);
            atomicAdd(&sums[cseg * 4 + 3], cc);
          }
          cseg = pfs; cx = 0.f; cy = 0.f; cz = 0.f; cc = 0.f;
        }
        cx += pf1; cy += pf2; cz += pf3; cc += 1.f;
      }
    }
    barrier_lgkm();

    // ---- issue next-tile prefetch; stays in flight across all barriers ----
    if (w == 0) {
      int p = (tile0 + ti + 1) * MT + lane;
      pfv = p < n;
      int pcl = pfv ? p : (n - 1);
      const float* pp = pc + (size_t)pcl * 5;
      pf1 = pp[1]; pf2 = pp[2]; pf3 = pp[3]; pfx = pp[4];
      pfs = sid[pcl];
    }

    // ---- layer 1: all 8 waves, 16 feats x own 32 points ----
    {
      f32x4 acc1[2];
      #pragma unroll
      for (int c = 0; c < 2; ++c) {
        bf16x8 ld = *reinterpret_cast<const bf16x8*>(&shF[pg * 32 + c * 16 + nn][0]);
        bf16x8 af = (q == 0) ? ld : zero8;
        acc1[c] = __builtin_amdgcn_mfma_f32_16x16x32_bf16(w1f, af, zero4, 0, 0, 0);
      }
      #pragma unroll
      for (int c = 0; c < 2; ++c) {
        bf16x4 pk;
        #pragma unroll
        for (int r = 0; r < 4; ++r)
          pk[r] = (__bf16)fmaxf(acc1[c][r] + b1r[r], 0.f);
        *reinterpret_cast<bf16x4*>(&sh1[pg * 32 + c * 16 + nn][fg * 16 + q * 4]) = pk;
      }
    }
    barrier_lgkm();

    // ---- layer 2: 32 feats x own 32 points; reads only own point-half ----
    {
      bf16x8 f2[2][2];           // [ks][c]
      #pragma unroll
      for (int ks = 0; ks < 2; ++ks)
        #pragma unroll
        for (int c = 0; c < 2; ++c)
          f2[ks][c] = *reinterpret_cast<const bf16x8*>(&sh1[pg * 32 + c * 16 + nn][ks * 32 + q * 8]);
      f32x4 acc2[2][2];
      #pragma unroll
      for (int mt = 0; mt < 2; ++mt)
        #pragma unroll
        for (int c = 0; c < 2; ++c) acc2[mt][c] = zero4;
      #pragma unroll
      for (int ks = 0; ks < 2; ++ks)
        #pragma unroll
        for (int mt = 0; mt < 2; ++mt)
          #pragma unroll
          for (int c = 0; c < 2; ++c)
            acc2[mt][c] = __builtin_amdgcn_mfma_f32_16x16x32_bf16(w2f[mt][ks], f2[ks][c], acc2[mt][c], 0, 0, 0);
      #pragma unroll
      for (int mt = 0; mt < 2; ++mt)
        #pragma unroll
        for (int c = 0; c < 2; ++c) {
          bf16x4 pk;
          #pragma unroll
          for (int r = 0; r < 4; ++r)
            pk[r] = (__bf16)fmaxf(acc2[mt][c][r] + b2r[mt][r], 0.f);
          *reinterpret_cast<bf16x4*>(&sh2[pg * 32 + c * 16 + nn][fg * 32 + mt * 16 + q * 4]) = pk;
        }
    }
    barrier_lgkm();

    // ---- layer 3: 64 feats x own 32 points; B-frags double-buffered over ks ----
    f32x4 acc3[4][2];
    #pragma unroll
    for (int mt = 0; mt < 4; ++mt)
      #pragma unroll
      for (int c = 0; c < 2; ++c) acc3[mt][c] = zero4;
    {
      bf16x8 fA0 = *reinterpret_cast<const bf16x8*>(&sh2[pg * 32 + 0 * 16 + nn][0 * 32 + q * 8]);
      bf16x8 fA1 = *reinterpret_cast<const bf16x8*>(&sh2[pg * 32 + 1 * 16 + nn][0 * 32 + q * 8]);
      #pragma unroll
      for (int ks = 0; ks < 4; ++ks) {
        bf16x8 nB0, nB1;
        if (ks < 3) {
          nB0 = *reinterpret_cast<const bf16x8*>(&sh2[pg * 32 + 0 * 16 + nn][(ks + 1) * 32 + q * 8]);
          nB1 = *reinterpret_cast<const bf16x8*>(&sh2[pg * 32 + 1 * 16 + nn][(ks + 1) * 32 + q * 8]);
        }
        #pragma unroll
        for (int mt = 0; mt < 4; ++mt) {
          acc3[mt][0] = __builtin_amdgcn_mfma_f32_16x16x32_bf16(w3f[mt][ks], fA0, acc3[mt][0], 0, 0, 0);
          acc3[mt][1] = __builtin_amdgcn_mfma_f32_16x16x32_bf16(w3f[mt][ks], fA1, acc3[mt][1], 0, 0, 0);
        }
        fA0 = nB0; fA1 = nB1;
      }
    }

    // ---- segment max (sorted ids; block-uniform control) ----
    int smin = segt[0], smax = segt[MT - 1];
    if (smin != s_cur) {           // previous segment ended exactly at tile edge
      flush4(run[0], run[1], run[2], run[3], s_cur, fg, q, nn, b3, pooled);
      #pragma unroll
      for (int mt = 0; mt < 4; ++mt) run[mt] = neginf4;
      s_cur = smin;
    }
    if (smin == smax) {
      // fast path: whole tile in one segment
      #pragma unroll
      for (int mt = 0; mt < 4; ++mt)
        #pragma unroll
        for (int r = 0; r < 4; ++r)
          run[mt][r] = fmaxf(run[mt][r], fmaxf(acc3[mt][0][r], acc3[mt][1][r]));
    } else {
      // slow path: tile crosses >=1 boundary (rare, ~255 total)
      int sg0 = segt[pg * 32 + nn], sg1 = segt[pg * 32 + 16 + nn];
      for (int s = smin; s <= smax; ++s) {
        f32x4 tmp[4];
        #pragma unroll
        for (int mt = 0; mt < 4; ++mt)
          #pragma unroll
          for (int r = 0; r < 4; ++r) {
            float v0 = (sg0 == s) ? acc3[mt][0][r] : -FLT_MAX;
            float v1 = (sg1 == s) ? acc3[mt][1][r] : -FLT_MAX;
            tmp[mt][r] = fmaxf(v0, v1);
          }
        if (s < smax) {
          if (s == s_cur) {
            #pragma unroll
            for (int mt = 0; mt < 4; ++mt)
              #pragma unroll
              for (int r = 0; r < 4; ++r) run[mt][r] = fmaxf(run[mt][r], tmp[mt][r]);
            flush4(run[0], run[1], run[2], run[3], s, fg, q, nn, b3, pooled);
            #pragma unroll
            for (int mt = 0; mt < 4; ++mt) run[mt] = neginf4;
          } else {
            flush4(tmp[0], tmp[1], tmp[2], tmp[3], s, fg, q, nn, b3, pooled);
          }
        } else {
          #pragma unroll
          for (int mt = 0; mt < 4; ++mt)
            #pragma unroll
            for (int r = 0; r < 4; ++r) run[mt][r] = fmaxf(run[mt][r], tmp[mt][r]);
        }
      }
      s_cur = smax;
    }
    barrier_lgkm();   // protect shF/segt/sh1/sh2 against next iteration's writes
  }
  flush4(run[0], run[1], run[2], run[3], s_cur, fg, q, nn, b3, pooled);

  // final centroid flush
  if (w == 0 && cc > 0.f) {
    atomicAdd(&sums[cseg * 4 + 0], cx);
    atomicAdd(&sums[cseg * 4 + 1], cy);
    atomicAdd(&sums[cseg * 4 + 2], cz);
    atomicAdd(&sums[cseg * 4 + 3], cc);
  }
}

// ---------------- head: pooled @ Wf + bf -> softplus, + centroid ----------------
__global__ void final_kernel(const float* __restrict__ sums, const unsigned* __restrict__ pooled,
                             const float* __restrict__ Wf, const float* __restrict__ bfv,
                             float* __restrict__ out) {
  __shared__ float red[4][3];
  int g = blockIdx.x;
  int t = threadIdx.x;   // 256 = LAT
  unsigned u = pooled[g * LAT + t];
  float f = u ? unmapf(u) : 0.f;
  float s0 = f * Wf[t * 3 + 0];
  float s1 = f * Wf[t * 3 + 1];
  float s2 = f * Wf[t * 3 + 2];
  #pragma unroll
  for (int off = 1; off < 64; off <<= 1) {
    s0 += __shfl_xor(s0, off);
    s1 += __shfl_xor(s1, off);
    s2 += __shfl_xor(s2, off);
  }
  int wave = t >> 6;
  if ((t & 63) == 0) { red[wave][0] = s0; red[wave][1] = s1; red[wave][2] = s2; }
  __syncthreads();
  if (t < 3) {
    float acc = bfv[t] + red[0][t] + red[1][t] + red[2][t] + red[3][t];
    float sp  = fmaxf(acc, 0.f) + log1pf(expf(-fabsf(acc)));
    float cnt = fmaxf(sums[g * 4 + 3], 1.f);
    float cen = sums[g * 4 + t] / cnt;
    out[g * 3 + t] = cen + sp;
  }
}

extern "C" void kernel_launch(void* const* d_in, const int* in_sizes, int n_in,
                              void* d_out, int out_size, void* d_ws, size_t ws_size,
                              hipStream_t stream) {
  const float* pc  = (const float*)d_in[0];
  const float* W1  = (const float*)d_in[1];
  const float* b1  = (const float*)d_in[2];
  const float* W2  = (const float*)d_in[3];
  const float* b2  = (const float*)d_in[4];
  const float* W3  = (const float*)d_in[5];
  const float* b3  = (const float*)d_in[6];
  const float* Wf  = (const float*)d_in[7];
  const float* bfv = (const float*)d_in[8];
  const int*   sid = (const int*)d_in[9];
  int n = in_sizes[0] / 5;

  float*    sums   = (float*)d_ws;                         // G*4 fp32
  unsigned* pooled = (unsigned*)((char*)d_ws + 4096);      // G*LAT mapped-uint maxes
  hipMemsetAsync(d_ws, 0, 4096 + (size_t)G * LAT * 4, stream);

  int tiles   = (n + MT - 1) / MT;
  int nblocks = 256;                         // 1 block/CU (VGPR-bound at ~200 regs)
  int tpb     = (tiles + nblocks - 1) / nblocks;
  mlp_kernel<<<nblocks, 512, 0, stream>>>(pc, W1, b1, W2, b2, W3, b3, sid, pooled, sums, n, tpb);

  final_kernel<<<G, 256, 0, stream>>>(sums, pooled, Wf, bfv, (float*)d_out);
}